// Round 1
// baseline (31.865 us; speedup 1.0000x reference)
//
#include <hip/hip_runtime.h>

// 45-tap palindromic filter, padded to 48 with zeros so every phase uses a
// uniform 12-tap loop: out phase p uses weight BASE48[4*j + 3 - p].
constexpr float BASE48[48] = {
    -0.00463495665f, -0.00363442646f, 3.84904063e-18f, 0.00576678319f, 0.0108358664f,
    0.010198079f, -9.31747402e-18f, -0.0175033181f, -0.0317660068f, -0.0284531643f,
    1.85181518e-17f, 0.0442450253f, 0.0771733386f, 0.067055491f, -2.85299239e-17f,
    -0.101548683f, -0.178708388f, -0.160004642f, 3.61741232e-17f, 0.287940558f,
    0.625431459f, 0.8970676f, 1.00107877f, 0.8970676f, 0.625431459f, 0.287940558f,
    3.61741232e-17f, -0.160004642f, -0.178708388f, -0.101548683f, -2.85299239e-17f,
    0.067055491f, 0.0771733386f, 0.0442450253f, 1.85181518e-17f, -0.0284531643f,
    -0.0317660068f, -0.0175033181f, -9.31747402e-18f, 0.010198079f, 0.0108358664f,
    0.00576678319f, 3.84904063e-18f, -0.00363442646f, -0.00463495665f,
    0.0f, 0.0f, 0.0f
};

__device__ __forceinline__ void fma4(float4& a, float w, const float4& v) {
    a.x = fmaf(w, v.x, a.x);
    a.y = fmaf(w, v.y, a.y);
    a.z = fmaf(w, v.z, a.z);
    a.w = fmaf(w, v.w, a.w);
}

// One block computes a 64x64 output tile for one (b,c) image.
// Output o (per axis): taps k ≡ (3 - (o&3)) mod 4; input i = o/4 - 5 + j.
// Input halo tile: rows/cols [O/4 - 5, O/4 + 21] -> 27 values.
__launch_bounds__(256)
__global__ void upfirdn4_sep_kernel(const float* __restrict__ x,
                                    float* __restrict__ out) {
    constexpr int H = 128, W = 128, OW = 512, OH = 512;

    __shared__ float in_s[27][28];   // 27x27 input halo (pad to 28 cols)
    __shared__ float tmp[27][64];    // after horizontal pass: 27 input-rows x 64 out-cols

    const int tid = threadIdx.x;
    const int bc  = blockIdx.z;               // b*8 + c
    const int OX  = blockIdx.x * 64;
    const int OY  = blockIdx.y * 64;
    const int I0x = (OX >> 2) - 5;
    const int I0y = (OY >> 2) - 5;

    const float* xb = x + (size_t)bc * (H * W);

    // ---- stage input halo tile (zero-pad out-of-range) ----
    for (int t = tid; t < 27 * 28; t += 256) {
        int r = t / 28;
        int c = t - r * 28;
        int iy = I0y + r;
        int ix = I0x + c;
        float v = 0.0f;
        if ((unsigned)iy < (unsigned)H && (unsigned)ix < (unsigned)W)
            v = xb[iy * W + ix];
        in_s[r][c] = v;
    }
    __syncthreads();

    // ---- horizontal polyphase pass: tmp[row][oc], oc in [0,64) ----
    // Each work item computes 4 consecutive output cols (phases 0..3) sharing
    // the same 12 input samples in_s[row][m..m+11].
    for (int t = tid; t < 27 * 16; t += 256) {
        int row = t >> 4;
        int m   = t & 15;
        float a0 = 0.f, a1 = 0.f, a2 = 0.f, a3 = 0.f;
#pragma unroll
        for (int j = 0; j < 12; ++j) {
            float v = in_s[row][m + j];
            a0 = fmaf(BASE48[4 * j + 3], v, a0);  // phase 0
            a1 = fmaf(BASE48[4 * j + 2], v, a1);  // phase 1
            a2 = fmaf(BASE48[4 * j + 1], v, a2);  // phase 2
            a3 = fmaf(BASE48[4 * j + 0], v, a3);  // phase 3
        }
        *(float4*)&tmp[row][m << 2] = make_float4(a0, a1, a2, a3);
    }
    __syncthreads();

    // ---- vertical polyphase pass: each thread does a 4x4 output patch ----
    // Thread -> (m = out-row-group 0..15, oc = 4*(tid&15)). The four output
    // rows 4m+p all read tmp rows [m, m+11]: 12 shared float4 LDS reads.
    {
        int m  = tid >> 4;
        int oc = (tid & 15) << 2;
        float4 acc0 = {0, 0, 0, 0}, acc1 = {0, 0, 0, 0};
        float4 acc2 = {0, 0, 0, 0}, acc3 = {0, 0, 0, 0};
#pragma unroll
        for (int j = 0; j < 12; ++j) {
            float4 v = *(const float4*)&tmp[m + j][oc];
            fma4(acc0, BASE48[4 * j + 3], v);  // phase 0
            fma4(acc1, BASE48[4 * j + 2], v);  // phase 1
            fma4(acc2, BASE48[4 * j + 1], v);  // phase 2
            fma4(acc3, BASE48[4 * j + 0], v);  // phase 3
        }
        size_t base = (size_t)bc * (OH * OW) + (size_t)(OY + (m << 2)) * OW + (OX + oc);
        *(float4*)&out[base]          = acc0;
        *(float4*)&out[base + OW]     = acc1;
        *(float4*)&out[base + 2 * OW] = acc2;
        *(float4*)&out[base + 3 * OW] = acc3;
    }
}

extern "C" void kernel_launch(void* const* d_in, const int* in_sizes, int n_in,
                              void* d_out, int out_size, void* d_ws, size_t ws_size,
                              hipStream_t stream) {
    const float* x = (const float*)d_in[0];
    float* out = (float*)d_out;
    dim3 grid(8, 8, 128);   // 8x8 tiles of 64x64 over 512x512, z = B*C = 128
    dim3 block(256);
    upfirdn4_sep_kernel<<<grid, block, 0, stream>>>(x, out);
}